// Round 5
// baseline (5557.178 us; speedup 1.0000x reference)
//
#include <hip/hip_runtime.h>

typedef unsigned short u16;
typedef unsigned int   u32;
typedef unsigned long long u64;
typedef short v8s __attribute__((ext_vector_type(8)));
typedef float v16f __attribute__((ext_vector_type(16)));

#define B_ 512
#define I_ 128
#define H_ 512
#define KK 640
#define NSTEP 512
#define AST 648   // A-tile row stride, u16 elems (1296 B = 324 dw, 324%32=4 -> even bank spread)

__device__ inline u16 f2b(float x){
  union{float f; unsigned u;} v; v.f = x;
  unsigned r = v.u + 0x7fffu + ((v.u >> 16) & 1u);
  return (u16)(r >> 16);
}

// overflow-safe fast tanh: x->+inf => 1, x->-inf => -1 (exp underflow)
__device__ inline float tanh_fast(float x){
  float e = __expf(2.f * x);
  return 1.f - 2.f / (e + 1.f);
}

template<int CTRL>
__device__ inline float dppf(float x){
  int i = __builtin_amdgcn_update_dpp(0, __float_as_int(x), CTRL, 0xF, 0xF, true);
  return __int_as_float(i);
}

// All cross-wg traffic: relaxed agent-scope atomics -> L3 = coherence point.
__device__ inline u64 ld64(const u16* p){
  return __hip_atomic_load((const u64*)p, __ATOMIC_RELAXED, __HIP_MEMORY_SCOPE_AGENT);
}
__device__ inline void st32(u16* p, u32 v){
  __hip_atomic_store((u32*)p, v, __ATOMIC_RELAXED, __HIP_MEMORY_SCOPE_AGENT);
}
__device__ inline u32 fpoll(const u32* p){
  return __hip_atomic_load(p, __ATOMIC_RELAXED, __HIP_MEMORY_SCOPE_AGENT);
}
__device__ inline void fst(u32* p, u32 v){
  __hip_atomic_store(p, v, __ATOMIC_RELAXED, __HIP_MEMORY_SCOPE_AGENT);
}

// Prep: Wcat[gcol][k] = [W_hh (k<512) | W_ih (k>=512)] bf16, fcW bf16, fused
// bias, h0 bf16, out0 = x[511] bf16, zeroed flags. Re-runs every call.
__global__ void init_kernel(const float* __restrict__ x, const float* __restrict__ h0,
    const float* __restrict__ Wih, const float* __restrict__ Whh,
    const float* __restrict__ bih, const float* __restrict__ bhh, const float* __restrict__ fcW,
    u16* __restrict__ Wcat, u16* __restrict__ fcWb, float* __restrict__ bsum,
    u16* __restrict__ hb0, u16* __restrict__ outb, u32* __restrict__ flags)
{
  int idx = blockIdx.x * 256 + threadIdx.x;
  if (idx < 1310720) {                       // Wcat: 2048 x 640, [Whh | Wih]
    int g = idx / 640, k = idx - g * 640;
    float v = (k < 512) ? Whh[g * 512 + k] : Wih[g * 128 + (k - 512)];
    Wcat[idx] = f2b(v);
  } else if (idx < 1376256) {                // fcW bf16: 128 x 512
    int i = idx - 1310720; fcWb[i] = f2b(fcW[i]);
  } else if (idx < 1378304) {                // fused bias: 2048
    int i = idx - 1376256; bsum[i] = bih[i] + bhh[i];
  } else if (idx < 1640448) {                // h init: 512 x 512
    int i = idx - 1378304; hb0[i] = f2b(h0[i]);
  } else if (idx < 1705984) {                // inp init = x[511]: 512 x 128
    int i = idx - 1640448; outb[i] = f2b(x[33488896 + i]);
  } else if (idx < 1707008) {                // flags[16 groups][16 wg x 4 wave]
    flags[idx - 1705984] = 0u;
  }
}

// Persistent decoder, grid = 256 x 512 threads (1 wg/CU, 8 waves = 2/SIMD).
// 16 groups x 16 wgs; group mb owns rows mb*32..+32, wg nb owns h-cols
// nb*32..+32.
// Gate wave wid (0..3) computes ALL FOUR gates for 8 h-cols
// [nb*32+8*wid .. +8): B-col c -> gate (c&3), h-col (c>>2) (weight rows
// permuted at load). Cell is wave-local: 4 DPP quad_perm broadcasts gather
// i,f,g,o per h-col, c-state in 16 regs/lane, packed-u32 h store (neighbor
// col via DPP ROW_SHL:4 = 0x104, out[i]=in[i+4]; R4's 0x114 ROW_SHR read
// i-4 -> empirically confirmed wrong direction). 2 barriers/step.
// h handoff: per-WAVE s_waitcnt vmcnt(0) + per-wave flag [nb*4+wid];
// consumers poll 8 sub-flags for their 64-col gather slice.
// Waves 4-7: redundant local fc (out-cols (wid-4)*32..+32, k=512), dout
// stores deferred to next iteration's poll/gather window.
__global__ __launch_bounds__(512, 2) void decoder_persist(
    const u16* __restrict__ Wcat, const float* __restrict__ bsum,
    const u16* __restrict__ fcWb, const float* __restrict__ fcb,
    const float* __restrict__ c0,
    u16* __restrict__ hb0, u16* __restrict__ hb1, const u16* __restrict__ outb,
    float* __restrict__ dout, u32* __restrict__ flags)
{
  __shared__ __align__(16) u16 Alds[32 * AST];   // 32 x (512 h | 128 out | 8 pad)

  const int tid  = threadIdx.x;
  const int wid  = tid >> 6, lane = tid & 63;
  const int l31  = lane & 31, q2 = lane >> 5;     // MFMA: col = lane&31, row-half = lane>>5
  const int mb   = blockIdx.x & 15;               // group (co-XCD under round-robin; perf-only)
  const int nb   = blockIdx.x >> 4;               // col-slice 0..15
  const int R    = mb * 32;
  u32* gf = flags + mb * 64;                      // 64 flags/group: [nb*4 + wave]

  const bool isfc = (wid >= 4);
  const int  wc   = (wid - 4) * 32;               // fc out-col base (fc waves only)

  // gate-wave B mapping: B-col c -> gate (c&3), h-col nb*32 + wid*8 + (c>>2)
  const int ggate = l31 & 3, gj = l31 >> 2;       // per-lane gate, local h-col
  const int gcol  = ggate * 512 + nb * 32 + wid * 8 + gj;   // Wcat row

  // ---- resident weights: 40 x v8s = 160 regs/lane ----
  v8s wfrag[40];
  if (!isfc) {
    const u16* wr = Wcat + (u64)gcol * KK + q2 * 8;
    #pragma unroll
    for (int kc = 0; kc < 40; ++kc) wfrag[kc] = *reinterpret_cast<const v8s*>(wr + kc * 16);
  } else {
    const u16* fr = fcWb + (u64)(wc + l31) * H_ + q2 * 8;
    #pragma unroll
    for (int kc = 0; kc < 32; ++kc) wfrag[kc] = *reinterpret_cast<const v8s*>(fr + kc * 16);
    #pragma unroll
    for (int kc = 32; kc < 40; ++kc) wfrag[kc] = (v8s){0,0,0,0,0,0,0,0};
  }
  const float bias0 = isfc ? fcb[wc + l31] : bsum[gcol];

  // dout ownership: out-col (wc+l31) written by wg nb == col>>3 (8 cols/wg)
  const bool dopred = isfc && (((wc + l31) >> 3) == nb);

  // deferred dout state: 16 outputs of fc-act held in regs, flushed next iter
  float oreg[16];
  float* dpend = nullptr;

  // c state (gate waves): c for h-col gj at the lane's 16 rows (x4 redundant
  // per quad -- every lane carries it so the dpp cell needs no predication)
  float cv[16];
  if (!isfc) {
    #pragma unroll
    for (int r = 0; r < 16; ++r) {
      int row = (r & 3) + 8 * (r >> 2) + 4 * q2;
      cv[r] = c0[(R + row) * H_ + nb * 32 + wid * 8 + gj];
    }
  }

  const float anum  = (ggate == 2) ? -2.f : 1.f;  // act = abase + anum/(e+1)
  const float abase = (ggate == 2) ?  1.f : 0.f;
  const float zmul  = (ggate == 2) ?  2.f : -1.f; // e = exp(zmul*z)

  for (int t = 0; t <= NSTEP; ++t) {
    const u16* hsrc = (t & 1) ? hb1 : hb0;

    // ---- flush deferred dout (fire-and-forget; drains during poll/gather) --
    if (dopred && dpend) {
      #pragma unroll
      for (int r = 0; r < 16; ++r) {
        int row = (r & 3) + 8 * (r >> 2) + 4 * q2;
        __builtin_nontemporal_store(oreg[r], dpend + (R + row) * I_ + wc + l31);
      }
      dpend = nullptr;
    }

    // ---- per-wave poll: 8 sub-flags cover gather slice [64*wid..+64) ----
    if (t > 0) {
      const u32 tt = (u32)t;
      for (;;) {
        u32 f = fpoll(gf + 8 * wid + (lane & 7));
        if (__all((int)(f >= tt))) break;
      }
      __asm__ volatile("" ::: "memory");
    }

    // ---- gather: wave w stages h-cols [64w, 64w+64): 8 u64/lane ----
    {
      u64 tmp[8];
      #pragma unroll
      for (int k = 0; k < 8; ++k) {
        int v = k * 64 + lane;
        int row = v >> 4, c16 = v & 15;
        tmp[k] = ld64(hsrc + (R + row) * H_ + wid * 64 + c16 * 4);
      }
      #pragma unroll
      for (int k = 0; k < 8; ++k) {
        int v = k * 64 + lane;
        int row = v >> 4, c16 = v & 15;
        *reinterpret_cast<u64*>(&Alds[row * AST + wid * 64 + c16 * 4]) = tmp[k];
      }
    }
    if (t == 0) {                       // out(-1) = x[511] (preconverted)
      u64 tmp[2];
      #pragma unroll
      for (int u = 0; u < 2; ++u) {
        int v = u * 512 + tid;
        int row = v >> 5, cc = v & 31;
        tmp[u] = ld64(outb + (R + row) * I_ + cc * 4);
      }
      #pragma unroll
      for (int u = 0; u < 2; ++u) {
        int v = u * 512 + tid;
        int row = v >> 5, cc = v & 31;
        *reinterpret_cast<u64*>(&Alds[row * AST + 512 + cc * 4]) = tmp[u];
      }
    }
    __syncthreads();                    // bar A: A-tile h-region ready
                                        // (also orders: phase-2 out-reads of
                                        //  t-1 done before fc rewrites out)

    // ---- phase 1: k = 0..512 (h part), identical for gate and fc waves ----
    v16f acc = {0.f,0.f,0.f,0.f,0.f,0.f,0.f,0.f,0.f,0.f,0.f,0.f,0.f,0.f,0.f,0.f};
    const u16* ab = &Alds[l31 * AST + q2 * 8];
    __builtin_amdgcn_s_setprio(1);
    #pragma unroll
    for (int kc = 0; kc < 32; ++kc) {
      v8s a = *reinterpret_cast<const v8s*>(ab + kc * 16);
      acc = __builtin_amdgcn_mfma_f32_32x32x16_bf16(a, wfrag[kc], acc, 0, 0, 0);
    }
    __builtin_amdgcn_s_setprio(0);

    // ---- fc act: out(t-1) = 2*sigmoid(.)-1 -> LDS feedback + oreg ----
    if (isfc && t > 0) {
      #pragma unroll
      for (int r = 0; r < 16; ++r) {
        int row = (r & 3) + 8 * (r >> 2) + 4 * q2;   // 32x32 C-layout
        float o = 2.f / (1.f + __expf(-(acc[r] + bias0))) - 1.f;
        oreg[r] = o;
        Alds[row * AST + 512 + wc + l31] = f2b(o);
      }
      dpend = dout + (u64)(NSTEP - t) * (B_ * I_);
    }
    __syncthreads();                    // bar B: out region ready; all h-reads done

    if (t < NSTEP) {
      if (!isfc) {
        // ---- phase 2: k = 512..640 (out part) ----
        __builtin_amdgcn_s_setprio(1);
        #pragma unroll
        for (int kc = 32; kc < 40; ++kc) {
          v8s a = *reinterpret_cast<const v8s*>(ab + kc * 16);
          acc = __builtin_amdgcn_mfma_f32_32x32x16_bf16(a, wfrag[kc], acc, 0, 0, 0);
        }
        __builtin_amdgcn_s_setprio(0);

        // ---- in-wave cell: dpp quad broadcast of i,f,g,o, h -> L3 ----
        u16* hdst = (t & 1) ? hb0 : hb1;
        #pragma unroll
        for (int r = 0; r < 16; ++r) {
          int row = (r & 3) + 8 * (r >> 2) + 4 * q2;
          float z = acc[r] + bias0;
          float e = __expf(zmul * z);
          float act = abase + anum / (e + 1.f);     // sigmoid or tanh by gate
          float ig = dppf<0x00>(act);               // quad_perm broadcast lane 0
          float fg = dppf<0x55>(act);               // lane 1
          float gg = dppf<0xAA>(act);               // lane 2
          float og = dppf<0xFF>(act);               // lane 3
          float cn = fg * cv[r] + ig * gg;
          cv[r] = cn;
          float h = og * tanh_fast(cn);
          float hn = dppf<0x104>(h);                // ROW_SHL:4 -> in[i+4] = col gj+1's h
          if ((l31 & 7) == 0) {                     // one store lane per col-pair
            u32 packed = (u32)f2b(h) | ((u32)f2b(hn) << 16);
            st32(hdst + (R + row) * H_ + nb * 32 + wid * 8 + gj, packed);
          }
        }
        __asm__ volatile("s_waitcnt vmcnt(0)" ::: "memory");   // wave-local drain
        if (lane == 0) fst(gf + nb * 4 + wid, (u32)(t + 1));
      }
    }
  }

  // ---- final dout flush (out(511), computed at t = NSTEP) ----
  if (dopred && dpend) {
    #pragma unroll
    for (int r = 0; r < 16; ++r) {
      int row = (r & 3) + 8 * (r >> 2) + 4 * q2;
      __builtin_nontemporal_store(oreg[r], dpend + (R + row) * I_ + wc + l31);
    }
  }
}

extern "C" void kernel_launch(void* const* d_in, const int* in_sizes, int n_in,
                              void* d_out, int out_size, void* d_ws, size_t ws_size,
                              hipStream_t stream)
{
  const float* x   = (const float*)d_in[0];
  // d_in[1] = enc_hiddens: unused by the reference
  const float* h0  = (const float*)d_in[2];
  const float* c0  = (const float*)d_in[3];
  const float* Wih = (const float*)d_in[4];
  const float* Whh = (const float*)d_in[5];
  const float* bih = (const float*)d_in[6];
  const float* bhh = (const float*)d_in[7];
  const float* fcW = (const float*)d_in[8];
  const float* fcb = (const float*)d_in[9];

  char* p = (char*)d_ws;
  u16*   Wcat  = (u16*)p;   p += 2048LL * 640 * 2;
  u16*   fcWb  = (u16*)p;   p += 128 * 512 * 2;
  float* bsum  = (float*)p; p += 2048 * 4;
  u16*   hb0   = (u16*)p;   p += 512 * 512 * 2;
  u16*   hb1   = (u16*)p;   p += 512 * 512 * 2;
  u16*   outb  = (u16*)p;   p += 512 * 128 * 2;
  u32*   flags = (u32*)p;   p += 1024 * 4;
  float* dout  = (float*)d_out;

  init_kernel<<<6672, 256, 0, stream>>>(x, h0, Wih, Whh, bih, bhh, fcW,
                                        Wcat, fcWb, bsum, hb0, outb, flags);
  decoder_persist<<<256, 512, 0, stream>>>(Wcat, bsum, fcWb, fcb, c0,
                                           hb0, hb1, outb, dout, flags);
}

// Round 6
// 3548.120 us; speedup vs baseline: 1.5662x; 1.5662x over previous
//
#include <hip/hip_runtime.h>

typedef unsigned short u16;
typedef unsigned int   u32;
typedef unsigned long long u64;
typedef short v8s __attribute__((ext_vector_type(8)));
typedef float v16f __attribute__((ext_vector_type(16)));
typedef float v2f  __attribute__((ext_vector_type(2)));

#define B_ 512
#define I_ 128
#define H_ 512
#define KK 640
#define NSTEP 512
#define AST 648   // A-tile row stride, u16 elems (1296 B = 324 dw, 324%32=4 -> even bank spread)

__device__ inline u16 f2b(float x){
  union{float f; unsigned u;} v; v.f = x;
  unsigned r = v.u + 0x7fffu + ((v.u >> 16) & 1u);
  return (u16)(r >> 16);
}

// overflow-safe fast tanh
__device__ inline float tanh_fast(float x){
  float e = __expf(2.f * x);
  return 1.f - 2.f / (e + 1.f);
}

// Agent-scope (sc0 sc1, L3 coherence point) — used ONLY for flags.
__device__ inline u64 ld64(const u16* p){
  return __hip_atomic_load((const u64*)p, __ATOMIC_RELAXED, __HIP_MEMORY_SCOPE_AGENT);
}
__device__ inline u32 fpoll(const u32* p){
  return __hip_atomic_load(p, __ATOMIC_RELAXED, __HIP_MEMORY_SCOPE_AGENT);
}
__device__ inline void fst(u32* p, u32 v){
  __hip_atomic_store(p, v, __ATOMIC_RELAXED, __HIP_MEMORY_SCOPE_AGENT);
}

// Prep: Wcat[gcol][k] = [W_hh (k<512) | W_ih (k>=512)] bf16, fcW bf16, fused
// bias, h0 bf16, out0 = x[511] bf16, zeroed flags + 8 XCD claim counters.
__global__ void init_kernel(const float* __restrict__ x, const float* __restrict__ h0,
    const float* __restrict__ Wih, const float* __restrict__ Whh,
    const float* __restrict__ bih, const float* __restrict__ bhh, const float* __restrict__ fcW,
    u16* __restrict__ Wcat, u16* __restrict__ fcWb, float* __restrict__ bsum,
    u16* __restrict__ hb0, u16* __restrict__ outb, u32* __restrict__ flags)
{
  int idx = blockIdx.x * 256 + threadIdx.x;
  if (idx < 1310720) {                       // Wcat: 2048 x 640, [Whh | Wih]
    int g = idx / 640, k = idx - g * 640;
    float v = (k < 512) ? Whh[g * 512 + k] : Wih[g * 128 + (k - 512)];
    Wcat[idx] = f2b(v);
  } else if (idx < 1376256) {                // fcW bf16: 128 x 512
    int i = idx - 1310720; fcWb[i] = f2b(fcW[i]);
  } else if (idx < 1378304) {                // fused bias: 2048
    int i = idx - 1376256; bsum[i] = bih[i] + bhh[i];
  } else if (idx < 1640448) {                // h init: 512 x 512
    int i = idx - 1378304; hb0[i] = f2b(h0[i]);
  } else if (idx < 1705984) {                // inp init = x[511]: 512 x 128
    int i = idx - 1640448; outb[i] = f2b(x[33488896 + i]);
  } else if (idx < 1706248) {                // flags[16][16] + 8 claim counters
    flags[idx - 1705984] = 0u;
  }
}

// Persistent decoder, grid = 256 x 512 threads (1 wg/CU, 8 waves = 2/SIMD).
// R6 = R3 (2770us) + XCD-local h exchange:
//  * Dynamic claim: 1 wg/CU is resource-forced => exactly 32 wgs/XCD. Each wg
//    reads HW_REG_XCC_ID, atomicAdd's its XCD counter -> slot in [0,32);
//    group mb = xcd*2 + slot/16, col-slice nb = slot&15. All 16 wgs of a
//    group are co-XCD BY CONSTRUCTION (no dispatch-mapping assumption).
//  * h data moves with sc0-only (L1-bypass, XCD-L2-coherent) asm load/store:
//    store-drain waits L2-ack not L3-ack; gathers are L2 hits; h never
//    crosses the fabric. Flags stay agent-scope (sc0 sc1) -> a wrong sc0
//    model shows as absmax failure, never a hang.
// Everything else identical to R3: waves 0-3 gates (k=640), waves 4-7
// redundant local fc (k=512), gbuf cell exchange, deferred dout flush.
__global__ __launch_bounds__(512, 2) void decoder_persist(
    const u16* __restrict__ Wcat, const float* __restrict__ bsum,
    const u16* __restrict__ fcWb, const float* __restrict__ fcb,
    const float* __restrict__ c0,
    u16* __restrict__ hb0, u16* __restrict__ hb1, const u16* __restrict__ outb,
    float* __restrict__ dout, u32* __restrict__ flags, u32* __restrict__ xcnt)
{
  __shared__ __align__(16) u16  Alds[32 * AST];   // 32 x (512 h | 128 out | 8 pad)
  __shared__ __align__(16) float gbuf[4096];      // 4 gates x 32 x 32 exchange
  __shared__ u32 claim_sh;

  const int tid  = threadIdx.x;
  const int wid  = tid >> 6, lane = tid & 63;
  const int l31  = lane & 31, q2 = lane >> 5;

  // ---- XCD claim: slot -> (mb, nb), co-XCD groups by construction ----
  if (tid == 0) {
    u32 xcc;
    asm volatile("s_getreg_b32 %0, hwreg(HW_REG_XCC_ID)" : "=s"(xcc));
    u32 slot = atomicAdd(xcnt + (xcc & 7), 1u);
    claim_sh = (xcc & 7) * 32 + (slot & 31);
  }
  __syncthreads();
  const int mb = (int)(claim_sh >> 4);            // group 0..15
  const int nb = (int)(claim_sh & 15);            // col-slice 0..15
  const int R  = mb * 32;
  u32* gf = flags + mb * 16;

  const bool isfc = (wid >= 4);
  const int  wc   = (wid - 4) * 32;               // fc out-col base

  // ---- resident weights: 40 x v8s = 160 regs/lane ----
  v8s wfrag[40];
  if (!isfc) {
    const u16* wr = Wcat + (u64)(wid * 512 + nb * 32 + l31) * KK + q2 * 8;
    #pragma unroll
    for (int kc = 0; kc < 40; ++kc) wfrag[kc] = *reinterpret_cast<const v8s*>(wr + kc * 16);
  } else {
    const u16* fr = fcWb + (u64)(wc + l31) * H_ + q2 * 8;
    #pragma unroll
    for (int kc = 0; kc < 32; ++kc) wfrag[kc] = *reinterpret_cast<const v8s*>(fr + kc * 16);
    #pragma unroll
    for (int kc = 32; kc < 40; ++kc) wfrag[kc] = (v8s){0,0,0,0,0,0,0,0};
  }
  const float bias0 = isfc ? fcb[wc + l31] : bsum[wid * 512 + nb * 32 + l31];

  const bool dopred = isfc && (((wc + l31) >> 3) == nb);

  float oreg[16];
  float* dpend = nullptr;

  const int crow = tid >> 4, ccol = (tid * 2) & 31;
  float cv0 = c0[(R + crow) * H_ + nb * 32 + ccol];
  float cv1 = c0[(R + crow) * H_ + nb * 32 + ccol + 1];

  for (int t = 0; t <= NSTEP; ++t) {
    const u16* hsrc = (t & 1) ? hb1 : hb0;

    // ---- flush deferred dout (drains during poll/gather window) ----
    if (dopred && dpend) {
      #pragma unroll
      for (int r = 0; r < 16; ++r) {
        int row = (r & 3) + 8 * (r >> 2) + 4 * q2;
        __builtin_nontemporal_store(oreg[r], dpend + (R + row) * I_ + wc + l31);
      }
      dpend = nullptr;
    }

    // ---- per-wave poll (agent scope): flags {2w, 2w+1} for its slice ----
    if (t > 0) {
      const u32 tt = (u32)t;
      for (;;) {
        u32 f = fpoll(gf + 2 * wid + (lane & 1));
        if (__all((int)(f >= tt))) break;
      }
      __asm__ volatile("" ::: "memory");
    }

    // ---- gather: wave w stages h-cols [64w, 64w+64), sc0-only (XCD L2) ----
    {
      const int rb = lane >> 4, c16 = lane & 15;  // addr_k = base + k*4*H_
      const u16* pb = hsrc + (u64)(R + rb) * H_ + wid * 64 + c16 * 4;
      const u16 *p0 = pb,            *p1 = pb + 4*H_,  *p2 = pb + 8*H_,  *p3 = pb + 12*H_;
      const u16 *p4 = pb + 16*H_,    *p5 = pb + 20*H_, *p6 = pb + 24*H_, *p7 = pb + 28*H_;
      u64 t0,t1,t2,t3,t4,t5,t6,t7;
      asm volatile(
        "global_load_dwordx2 %[d0], %[a0], off sc0\n\t"
        "global_load_dwordx2 %[d1], %[a1], off sc0\n\t"
        "global_load_dwordx2 %[d2], %[a2], off sc0\n\t"
        "global_load_dwordx2 %[d3], %[a3], off sc0\n\t"
        "global_load_dwordx2 %[d4], %[a4], off sc0\n\t"
        "global_load_dwordx2 %[d5], %[a5], off sc0\n\t"
        "global_load_dwordx2 %[d6], %[a6], off sc0\n\t"
        "global_load_dwordx2 %[d7], %[a7], off sc0\n\t"
        "s_waitcnt vmcnt(0)"
        : [d0]"=&v"(t0),[d1]"=&v"(t1),[d2]"=&v"(t2),[d3]"=&v"(t3),
          [d4]"=&v"(t4),[d5]"=&v"(t5),[d6]"=&v"(t6),[d7]"=&v"(t7)
        : [a0]"v"(p0),[a1]"v"(p1),[a2]"v"(p2),[a3]"v"(p3),
          [a4]"v"(p4),[a5]"v"(p5),[a6]"v"(p6),[a7]"v"(p7)
        : "memory");
      u16* lb = &Alds[rb * AST + wid * 64 + c16 * 4];
      *reinterpret_cast<u64*>(lb              ) = t0;
      *reinterpret_cast<u64*>(lb +  4 * AST   ) = t1;
      *reinterpret_cast<u64*>(lb +  8 * AST   ) = t2;
      *reinterpret_cast<u64*>(lb + 12 * AST   ) = t3;
      *reinterpret_cast<u64*>(lb + 16 * AST   ) = t4;
      *reinterpret_cast<u64*>(lb + 20 * AST   ) = t5;
      *reinterpret_cast<u64*>(lb + 24 * AST   ) = t6;
      *reinterpret_cast<u64*>(lb + 28 * AST   ) = t7;
    }
    if (t == 0) {                       // out(-1) = x[511] (init-kernel data)
      u64 tmp[2];
      #pragma unroll
      for (int u = 0; u < 2; ++u) {
        int v = u * 512 + tid;
        int row = v >> 5, cc = v & 31;
        tmp[u] = ld64(outb + (R + row) * I_ + cc * 4);
      }
      #pragma unroll
      for (int u = 0; u < 2; ++u) {
        int v = u * 512 + tid;
        int row = v >> 5, cc = v & 31;
        *reinterpret_cast<u64*>(&Alds[row * AST + 512 + cc * 4]) = tmp[u];
      }
    }
    __syncthreads();                    // bar A: A-tile h-region ready

    // ---- phase 1: k = 0..512, identical for gate and fc waves ----
    v16f acc = {0.f,0.f,0.f,0.f,0.f,0.f,0.f,0.f,0.f,0.f,0.f,0.f,0.f,0.f,0.f,0.f};
    const u16* ab = &Alds[l31 * AST + q2 * 8];
    __builtin_amdgcn_s_setprio(1);
    #pragma unroll
    for (int kc = 0; kc < 32; ++kc) {
      v8s a = *reinterpret_cast<const v8s*>(ab + kc * 16);
      acc = __builtin_amdgcn_mfma_f32_32x32x16_bf16(a, wfrag[kc], acc, 0, 0, 0);
    }
    __builtin_amdgcn_s_setprio(0);

    // ---- fc act: out(t-1) = 2*sigmoid(.)-1 -> LDS feedback + oreg ----
    if (isfc && t > 0) {
      #pragma unroll
      for (int r = 0; r < 16; ++r) {
        int row = (r & 3) + 8 * (r >> 2) + 4 * q2;   // 32x32 C-layout
        float o = 2.f / (1.f + __expf(-(acc[r] + bias0))) - 1.f;
        oreg[r] = o;
        Alds[row * AST + 512 + wc + l31] = f2b(o);
      }
      dpend = dout + (u64)(NSTEP - t) * (B_ * I_);
    }
    __syncthreads();                    // bar B: out region ready

    if (t < NSTEP) {
      if (!isfc) {
        // ---- phase 2: k = 512..640 ----
        __builtin_amdgcn_s_setprio(1);
        #pragma unroll
        for (int kc = 32; kc < 40; ++kc) {
          v8s a = *reinterpret_cast<const v8s*>(ab + kc * 16);
          acc = __builtin_amdgcn_mfma_f32_32x32x16_bf16(a, wfrag[kc], acc, 0, 0, 0);
        }
        __builtin_amdgcn_s_setprio(0);
        // ---- gate activation -> gbuf ----
        #pragma unroll
        for (int r = 0; r < 16; ++r) {
          int row = (r & 3) + 8 * (r >> 2) + 4 * q2;
          float z = acc[r] + bias0;
          float a2 = (wid == 2) ? tanh_fast(z) : 1.f / (1.f + __expf(-z));
          gbuf[wid * 1024 + row * 32 + l31] = a2;
        }
      }
      __syncthreads();                  // bar C: gbuf ready

      // ---- cell: c in regs, h(t+1) coalesced u32 -> XCD L2 (sc0) ----
      u16* hdst = (t & 1) ? hb0 : hb1;
      v2f ig = *reinterpret_cast<const v2f*>(&gbuf[       crow * 32 + ccol]);
      v2f fg = *reinterpret_cast<const v2f*>(&gbuf[1024 + crow * 32 + ccol]);
      v2f gg = *reinterpret_cast<const v2f*>(&gbuf[2048 + crow * 32 + ccol]);
      v2f og = *reinterpret_cast<const v2f*>(&gbuf[3072 + crow * 32 + ccol]);
      float cn0 = fg[0] * cv0 + ig[0] * gg[0];
      float cn1 = fg[1] * cv1 + ig[1] * gg[1];
      cv0 = cn0; cv1 = cn1;
      u32 packed = (u32)f2b(og[0] * tanh_fast(cn0)) | ((u32)f2b(og[1] * tanh_fast(cn1)) << 16);
      u16* hp = hdst + (u64)(R + crow) * H_ + nb * 32 + ccol;
      asm volatile("global_store_dword %[p], %[v], off sc0"
                   :: [p]"v"(hp), [v]"v"(packed) : "memory");
      // asm store is outside the compiler's vmcnt scoreboard: drain explicitly
      asm volatile("s_waitcnt vmcnt(0)" ::: "memory");
      __syncthreads();                  // bar D: all waves' h in XCD L2
      __asm__ volatile("" ::: "memory");
      if (tid == 0) fst(gf + nb, (u32)(t + 1));
    }
  }

  // ---- final dout flush (out(511), computed at t = NSTEP) ----
  if (dopred && dpend) {
    #pragma unroll
    for (int r = 0; r < 16; ++r) {
      int row = (r & 3) + 8 * (r >> 2) + 4 * q2;
      __builtin_nontemporal_store(oreg[r], dpend + (R + row) * I_ + wc + l31);
    }
  }
}

extern "C" void kernel_launch(void* const* d_in, const int* in_sizes, int n_in,
                              void* d_out, int out_size, void* d_ws, size_t ws_size,
                              hipStream_t stream)
{
  const float* x   = (const float*)d_in[0];
  // d_in[1] = enc_hiddens: unused by the reference
  const float* h0  = (const float*)d_in[2];
  const float* c0  = (const float*)d_in[3];
  const float* Wih = (const float*)d_in[4];
  const float* Whh = (const float*)d_in[5];
  const float* bih = (const float*)d_in[6];
  const float* bhh = (const float*)d_in[7];
  const float* fcW = (const float*)d_in[8];
  const float* fcb = (const float*)d_in[9];

  char* p = (char*)d_ws;
  u16*   Wcat  = (u16*)p;   p += 2048LL * 640 * 2;
  u16*   fcWb  = (u16*)p;   p += 128 * 512 * 2;
  float* bsum  = (float*)p; p += 2048 * 4;
  u16*   hb0   = (u16*)p;   p += 512 * 512 * 2;
  u16*   hb1   = (u16*)p;   p += 512 * 512 * 2;
  u16*   outb  = (u16*)p;   p += 512 * 128 * 2;
  u32*   flags = (u32*)p;   p += 512 * 4;        // 256 flags + 8 counters
  u32*   xcnt  = flags + 256;
  float* dout  = (float*)d_out;

  init_kernel<<<6666, 256, 0, stream>>>(x, h0, Wih, Whh, bih, bhh, fcW,
                                        Wcat, fcWb, bsum, hb0, outb, flags);
  decoder_persist<<<256, 512, 0, stream>>>(Wcat, bsum, fcWb, fcb, c0,
                                           hb0, hb1, outb, dout, flags, xcnt);
}

// Round 7
// 2961.736 us; speedup vs baseline: 1.8763x; 1.1980x over previous
//
#include <hip/hip_runtime.h>

typedef unsigned short u16;
typedef unsigned int   u32;
typedef unsigned long long u64;
typedef short v8s __attribute__((ext_vector_type(8)));
typedef float v16f __attribute__((ext_vector_type(16)));
typedef float v2f  __attribute__((ext_vector_type(2)));

#define B_ 512
#define I_ 128
#define H_ 512
#define KK 640
#define NSTEP 512
#define AST 648   // A-tile row stride, u16 elems (1296 B = 324 dw, 324%32=4 -> even bank spread)

__device__ inline u16 f2b(float x){
  union{float f; unsigned u;} v; v.f = x;
  unsigned r = v.u + 0x7fffu + ((v.u >> 16) & 1u);
  return (u16)(r >> 16);
}

// overflow-safe fast tanh: x->+inf => 1, x->-inf => -1 (exp underflow)
__device__ inline float tanh_fast(float x){
  float e = __expf(2.f * x);
  return 1.f - 2.f / (e + 1.f);
}

// LDS-only barrier: orders LDS producer->consumer WITHOUT the vmcnt(0) drain
// that __syncthreads emits (which would serialize on in-flight global stores,
// e.g. the deferred dout stores' HBM acks). HK/m201-proven pattern.
__device__ inline void bar_lds(){
  asm volatile("s_waitcnt lgkmcnt(0)" ::: "memory");
  __builtin_amdgcn_s_barrier();
  asm volatile("" ::: "memory");
}

// All cross-wg traffic: relaxed agent-scope atomics -> L3 = coherence point.
__device__ inline u64 ld64(const u16* p){
  return __hip_atomic_load((const u64*)p, __ATOMIC_RELAXED, __HIP_MEMORY_SCOPE_AGENT);
}
__device__ inline void st32(u16* p, u32 v){
  __hip_atomic_store((u32*)p, v, __ATOMIC_RELAXED, __HIP_MEMORY_SCOPE_AGENT);
}
__device__ inline u32 fpoll(const u32* p){
  return __hip_atomic_load(p, __ATOMIC_RELAXED, __HIP_MEMORY_SCOPE_AGENT);
}
__device__ inline void fst(u32* p, u32 v){
  __hip_atomic_store(p, v, __ATOMIC_RELAXED, __HIP_MEMORY_SCOPE_AGENT);
}

// Prep: Wcat[gcol][k] = [W_hh (k<512) | W_ih (k>=512)] bf16, fcW bf16, fused
// bias, h0 bf16, out0 = x[511] bf16, zeroed flags. Re-runs every call.
__global__ void init_kernel(const float* __restrict__ x, const float* __restrict__ h0,
    const float* __restrict__ Wih, const float* __restrict__ Whh,
    const float* __restrict__ bih, const float* __restrict__ bhh, const float* __restrict__ fcW,
    u16* __restrict__ Wcat, u16* __restrict__ fcWb, float* __restrict__ bsum,
    u16* __restrict__ hb0, u16* __restrict__ outb, u32* __restrict__ flags)
{
  int idx = blockIdx.x * 256 + threadIdx.x;
  if (idx < 1310720) {                       // Wcat: 2048 x 640, [Whh | Wih]
    int g = idx / 640, k = idx - g * 640;
    float v = (k < 512) ? Whh[g * 512 + k] : Wih[g * 128 + (k - 512)];
    Wcat[idx] = f2b(v);
  } else if (idx < 1376256) {                // fcW bf16: 128 x 512
    int i = idx - 1310720; fcWb[i] = f2b(fcW[i]);
  } else if (idx < 1378304) {                // fused bias: 2048
    int i = idx - 1376256; bsum[i] = bih[i] + bhh[i];
  } else if (idx < 1640448) {                // h init: 512 x 512
    int i = idx - 1378304; hb0[i] = f2b(h0[i]);
  } else if (idx < 1705984) {                // inp init = x[511]: 512 x 128
    int i = idx - 1640448; outb[i] = f2b(x[33488896 + i]);
  } else if (idx < 1706240) {                // flags[16 groups][16 wgs]
    flags[idx - 1705984] = 0u;
  }
}

// Persistent decoder, grid = 256 x 512 threads (1 wg/CU, 8 waves = 2/SIMD).
// 16 groups x 16 wgs; group mb owns rows mb*32..+32, wg nb owns h-cols
// nb*32..+32. Waves 0-3: gate wid (i,f,g,o), 32x32 tile k=640. Waves 4-7:
// redundant local fc, out-cols (wid-4)*32..+32, k=512. Phase-1 (k<512) is
// the same loop for both roles.
// R7 deltas vs R3 (2770us): (a) bars A/B/C are raw s_barrier + lgkmcnt(0)
// only -- no vmcnt(0) drain, so deferred-dout HBM acks leave the critical
// path; only bar D (h handoff) drains vmem before the flag. (b) gather loads
// are ISSUED before the dout flush (sched_barrier pins order): in-order vmcnt
// retirement then never blocks the gather LDS writes on store acks.
__global__ __launch_bounds__(512, 2) void decoder_persist(
    const u16* __restrict__ Wcat, const float* __restrict__ bsum,
    const u16* __restrict__ fcWb, const float* __restrict__ fcb,
    const float* __restrict__ c0,
    u16* __restrict__ hb0, u16* __restrict__ hb1, const u16* __restrict__ outb,
    float* __restrict__ dout, u32* __restrict__ flags)
{
  __shared__ __align__(16) u16  Alds[32 * AST];   // 32 x (512 h | 128 out | 8 pad)
  __shared__ __align__(16) float gbuf[4096];      // 4 gates x 32 x 32 exchange

  const int tid  = threadIdx.x;
  const int wid  = tid >> 6, lane = tid & 63;
  const int l31  = lane & 31, q2 = lane >> 5;     // MFMA: col = lane&31, k-half = lane>>5
  const int mb   = blockIdx.x & 15;               // group (co-XCD under round-robin; perf-only)
  const int nb   = blockIdx.x >> 4;               // col-slice 0..15
  const int R    = mb * 32;
  u32* gf = flags + mb * 16;

  const bool isfc = (wid >= 4);
  const int  wc   = (wid - 4) * 32;               // fc out-col base (fc waves only)

  // ---- resident weights: 40 x v8s = 160 regs/lane (AGPR-backed) ----
  v8s wfrag[40];
  if (!isfc) {
    const u16* wr = Wcat + (u64)(wid * 512 + nb * 32 + l31) * KK + q2 * 8;
    #pragma unroll
    for (int kc = 0; kc < 40; ++kc) wfrag[kc] = *reinterpret_cast<const v8s*>(wr + kc * 16);
  } else {
    const u16* fr = fcWb + (u64)(wc + l31) * H_ + q2 * 8;
    #pragma unroll
    for (int kc = 0; kc < 32; ++kc) wfrag[kc] = *reinterpret_cast<const v8s*>(fr + kc * 16);
    #pragma unroll
    for (int kc = 32; kc < 40; ++kc) wfrag[kc] = (v8s){0,0,0,0,0,0,0,0};
  }
  const float bias0 = isfc ? fcb[wc + l31] : bsum[wid * 512 + nb * 32 + l31];

  // dout ownership: out-col (wc+l31) written by wg nb == col>>3 (8 cols/wg)
  const bool dopred = isfc && (((wc + l31) >> 3) == nb);

  // deferred dout state: 16 outputs of fc-act held in regs, flushed next iter
  float oreg[16];
  float* dpend = nullptr;

  // c state: 2 elems/thread: (crow, ccol..ccol+1) of the wg's 32x32 h-tile
  const int crow = tid >> 4, ccol = (tid * 2) & 31;
  float cv0 = c0[(R + crow) * H_ + nb * 32 + ccol];
  float cv1 = c0[(R + crow) * H_ + nb * 32 + ccol + 1];

  for (int t = 0; t <= NSTEP; ++t) {
    const u16* hsrc = (t & 1) ? hb1 : hb0;

    // ---- per-wave poll: wave w needs slices {2w, 2w+1} for its gather ----
    if (t > 0) {
      const u32 tt = (u32)t;
      for (;;) {
        u32 f = fpoll(gf + 2 * wid + (lane & 1));
        if (__all((int)(f >= tt))) break;
      }
      __asm__ volatile("" ::: "memory");
    }

    // ---- gather: ISSUE loads first ----
    u64 tmp[8];
    #pragma unroll
    for (int k = 0; k < 8; ++k) {
      int v = k * 64 + lane;
      int row = v >> 4, c16 = v & 15;
      tmp[k] = ld64(hsrc + (R + row) * H_ + wid * 64 + c16 * 4);
    }
    __builtin_amdgcn_sched_barrier(0);  // loads issued before the stores below

    // ---- flush deferred dout AFTER the loads: in-order vmcnt retirement
    //      means these store acks never gate the gather LDS writes ----
    if (dopred && dpend) {
      #pragma unroll
      for (int r = 0; r < 16; ++r) {
        int row = (r & 3) + 8 * (r >> 2) + 4 * q2;
        __builtin_nontemporal_store(oreg[r], dpend + (R + row) * I_ + wc + l31);
      }
      dpend = nullptr;
    }

    // ---- gather: LDS writes (wait only on the loads) ----
    #pragma unroll
    for (int k = 0; k < 8; ++k) {
      int v = k * 64 + lane;
      int row = v >> 4, c16 = v & 15;
      *reinterpret_cast<u64*>(&Alds[row * AST + wid * 64 + c16 * 4]) = tmp[k];
    }
    if (t == 0) {                       // out(-1) = x[511] (preconverted)
      u64 tp2[2];
      #pragma unroll
      for (int u = 0; u < 2; ++u) {
        int v = u * 512 + tid;
        int row = v >> 5, cc = v & 31;
        tp2[u] = ld64(outb + (R + row) * I_ + cc * 4);
      }
      #pragma unroll
      for (int u = 0; u < 2; ++u) {
        int v = u * 512 + tid;
        int row = v >> 5, cc = v & 31;
        *reinterpret_cast<u64*>(&Alds[row * AST + 512 + cc * 4]) = tp2[u];
      }
    }
    bar_lds();                          // bar A: A-tile h-region ready (LDS only)

    // ---- phase 1: k = 0..512 (h part), identical for gate and fc waves ----
    v16f acc = {0.f,0.f,0.f,0.f,0.f,0.f,0.f,0.f,0.f,0.f,0.f,0.f,0.f,0.f,0.f,0.f};
    const u16* ab = &Alds[l31 * AST + q2 * 8];
    __builtin_amdgcn_s_setprio(1);
    #pragma unroll
    for (int kc = 0; kc < 32; ++kc) {
      v8s a = *reinterpret_cast<const v8s*>(ab + kc * 16);
      acc = __builtin_amdgcn_mfma_f32_32x32x16_bf16(a, wfrag[kc], acc, 0, 0, 0);
    }
    __builtin_amdgcn_s_setprio(0);

    // ---- fc act: out(t-1) = 2*sigmoid(.)-1 -> LDS feedback + oreg ----
    if (isfc && t > 0) {
      #pragma unroll
      for (int r = 0; r < 16; ++r) {
        int row = (r & 3) + 8 * (r >> 2) + 4 * q2;   // 32x32 C-layout
        float o = 2.f / (1.f + __expf(-(acc[r] + bias0))) - 1.f;
        oreg[r] = o;
        Alds[row * AST + 512 + wc + l31] = f2b(o);
      }
      dpend = dout + (u64)(NSTEP - t) * (B_ * I_);
    }
    bar_lds();                          // bar B: out region ready (LDS only)

    if (t < NSTEP) {
      if (!isfc) {
        // ---- phase 2: k = 512..640 (out part) ----
        __builtin_amdgcn_s_setprio(1);
        #pragma unroll
        for (int kc = 32; kc < 40; ++kc) {
          v8s a = *reinterpret_cast<const v8s*>(ab + kc * 16);
          acc = __builtin_amdgcn_mfma_f32_32x32x16_bf16(a, wfrag[kc], acc, 0, 0, 0);
        }
        __builtin_amdgcn_s_setprio(0);
        // ---- gate activation -> gbuf ----
        #pragma unroll
        for (int r = 0; r < 16; ++r) {
          int row = (r & 3) + 8 * (r >> 2) + 4 * q2;
          float z = acc[r] + bias0;
          float a2 = (wid == 2) ? tanh_fast(z) : 1.f / (1.f + __expf(-z));
          gbuf[wid * 1024 + row * 32 + l31] = a2;
        }
      }
      bar_lds();                        // bar C: gbuf ready (LDS only)

      // ---- cell: c in regs, h(t+1) packed u32 -> L3 ----
      u16* hdst = (t & 1) ? hb0 : hb1;
      v2f ig = *reinterpret_cast<const v2f*>(&gbuf[       crow * 32 + ccol]);
      v2f fg = *reinterpret_cast<const v2f*>(&gbuf[1024 + crow * 32 + ccol]);
      v2f gg = *reinterpret_cast<const v2f*>(&gbuf[2048 + crow * 32 + ccol]);
      v2f og = *reinterpret_cast<const v2f*>(&gbuf[3072 + crow * 32 + ccol]);
      float cn0 = fg[0] * cv0 + ig[0] * gg[0];
      float cn1 = fg[1] * cv1 + ig[1] * gg[1];
      cv0 = cn0; cv1 = cn1;
      u32 packed = (u32)f2b(og[0] * tanh_fast(cn0)) | ((u32)f2b(og[1] * tanh_fast(cn1)) << 16);
      st32(hdst + (R + crow) * H_ + nb * 32 + ccol, packed);

      // bar D: h stores MUST be at the coherence point before the flag.
      asm volatile("s_waitcnt vmcnt(0) lgkmcnt(0)" ::: "memory");
      __builtin_amdgcn_s_barrier();
      asm volatile("" ::: "memory");
      if (tid == 0) fst(gf + nb, (u32)(t + 1));
    }
  }

  // ---- final dout flush (out(511), computed at t = NSTEP) ----
  if (dopred && dpend) {
    #pragma unroll
    for (int r = 0; r < 16; ++r) {
      int row = (r & 3) + 8 * (r >> 2) + 4 * q2;
      __builtin_nontemporal_store(oreg[r], dpend + (R + row) * I_ + wc + l31);
    }
  }
}

extern "C" void kernel_launch(void* const* d_in, const int* in_sizes, int n_in,
                              void* d_out, int out_size, void* d_ws, size_t ws_size,
                              hipStream_t stream)
{
  const float* x   = (const float*)d_in[0];
  // d_in[1] = enc_hiddens: unused by the reference
  const float* h0  = (const float*)d_in[2];
  const float* c0  = (const float*)d_in[3];
  const float* Wih = (const float*)d_in[4];
  const float* Whh = (const float*)d_in[5];
  const float* bih = (const float*)d_in[6];
  const float* bhh = (const float*)d_in[7];
  const float* fcW = (const float*)d_in[8];
  const float* fcb = (const float*)d_in[9];

  char* p = (char*)d_ws;
  u16*   Wcat  = (u16*)p;   p += 2048LL * 640 * 2;
  u16*   fcWb  = (u16*)p;   p += 128 * 512 * 2;
  float* bsum  = (float*)p; p += 2048 * 4;
  u16*   hb0   = (u16*)p;   p += 512 * 512 * 2;
  u16*   hb1   = (u16*)p;   p += 512 * 512 * 2;
  u16*   outb  = (u16*)p;   p += 512 * 128 * 2;
  u32*   flags = (u32*)p;   p += 256 * 4;
  float* dout  = (float*)d_out;

  init_kernel<<<6666, 256, 0, stream>>>(x, h0, Wih, Whh, bih, bhh, fcW,
                                        Wcat, fcWb, bsum, hb0, outb, flags);
  decoder_persist<<<256, 512, 0, stream>>>(Wcat, bsum, fcWb, fcb, c0,
                                           hb0, hb1, outb, dout, flags);
}

// Round 8
// 2811.744 us; speedup vs baseline: 1.9764x; 1.0533x over previous
//
#include <hip/hip_runtime.h>

typedef unsigned short u16;
typedef unsigned int   u32;
typedef unsigned long long u64;
typedef short v8s __attribute__((ext_vector_type(8)));
typedef float v16f __attribute__((ext_vector_type(16)));
typedef float v2f  __attribute__((ext_vector_type(2)));

#define B_ 512
#define I_ 128
#define H_ 512
#define KK 640
#define NSTEP 512
#define AST 648   // A-tile row stride, u16 elems (1296 B = 324 dw, 324%32=4 -> even bank spread)

__device__ inline u16 f2b(float x){
  union{float f; unsigned u;} v; v.f = x;
  unsigned r = v.u + 0x7fffu + ((v.u >> 16) & 1u);
  return (u16)(r >> 16);
}

// overflow-safe fast tanh: x->+inf => 1, x->-inf => -1 (exp underflow)
__device__ inline float tanh_fast(float x){
  float e = __expf(2.f * x);
  return 1.f - 2.f / (e + 1.f);
}

// Raw LDS-ordering barrier: s_waitcnt lgkmcnt(0) + s_barrier, NO vmcnt drain.
// Used ONLY for the A1/A2 gather pipeline so waves can cross with global
// loads still in flight. All compiler-generated ds ops are ordered by the
// lgkmcnt(0); the "memory" clobber stops code motion across it.
__device__ inline void bar_lds(){
  asm volatile("s_waitcnt lgkmcnt(0)" ::: "memory");
  __builtin_amdgcn_s_barrier();
  asm volatile("" ::: "memory");
}

// All cross-wg traffic: relaxed agent-scope atomics -> L3 = coherence point.
__device__ inline u64 ld64(const u16* p){
  return __hip_atomic_load((const u64*)p, __ATOMIC_RELAXED, __HIP_MEMORY_SCOPE_AGENT);
}
__device__ inline void st32(u16* p, u32 v){
  __hip_atomic_store((u32*)p, v, __ATOMIC_RELAXED, __HIP_MEMORY_SCOPE_AGENT);
}
__device__ inline u32 fpoll(const u32* p){
  return __hip_atomic_load(p, __ATOMIC_RELAXED, __HIP_MEMORY_SCOPE_AGENT);
}
__device__ inline void fst(u32* p, u32 v){
  __hip_atomic_store(p, v, __ATOMIC_RELAXED, __HIP_MEMORY_SCOPE_AGENT);
}

// Prep: Wcat[gcol][k] = [W_hh (k<512) | W_ih (k>=512)] bf16, fcW bf16, fused
// bias, h0 bf16, out0 = x[511] bf16, zeroed flags. Re-runs every call.
__global__ void init_kernel(const float* __restrict__ x, const float* __restrict__ h0,
    const float* __restrict__ Wih, const float* __restrict__ Whh,
    const float* __restrict__ bih, const float* __restrict__ bhh, const float* __restrict__ fcW,
    u16* __restrict__ Wcat, u16* __restrict__ fcWb, float* __restrict__ bsum,
    u16* __restrict__ hb0, u16* __restrict__ outb, u32* __restrict__ flags)
{
  int idx = blockIdx.x * 256 + threadIdx.x;
  if (idx < 1310720) {                       // Wcat: 2048 x 640, [Whh | Wih]
    int g = idx / 640, k = idx - g * 640;
    float v = (k < 512) ? Whh[g * 512 + k] : Wih[g * 128 + (k - 512)];
    Wcat[idx] = f2b(v);
  } else if (idx < 1376256) {                // fcW bf16: 128 x 512
    int i = idx - 1310720; fcWb[i] = f2b(fcW[i]);
  } else if (idx < 1378304) {                // fused bias: 2048
    int i = idx - 1376256; bsum[i] = bih[i] + bhh[i];
  } else if (idx < 1640448) {                // h init: 512 x 512
    int i = idx - 1378304; hb0[i] = f2b(h0[i]);
  } else if (idx < 1705984) {                // inp init = x[511]: 512 x 128
    int i = idx - 1640448; outb[i] = f2b(x[33488896 + i]);
  } else if (idx < 1706240) {                // flags[16 groups][16 wgs]
    flags[idx - 1705984] = 0u;
  }
}

// Persistent decoder, grid = 256 x 512 threads (1 wg/CU, 8 waves = 2/SIMD).
// 16 groups x 16 wgs; group mb owns rows mb*32..+32, wg nb owns h-cols
// nb*32..+32. Waves 0-3: gate wid (i,f,g,o), 32x32 tile k=640. Waves 4-7:
// redundant local fc, out-cols (wid-4)*32..+32, k=512. Phase-1 (k<512) is
// the same loop for both roles.
// R8 = R3 (2770us) + split-gather pipeline: phase-1 consumes the A-tile in
// column order, so bar A becomes A1/A2. All waves poll + issue loads; waves
// 0-3 (cols 0-255) commit to LDS immediately; bar A1 (lgkm-only -- waves 4-7
// cross with loads in flight); phase-1a (kc 0-15, reads cols 0-255) hides
// waves 4-7's load latency; they commit; bar A2; phase-1b (kc 16-31).
// Everything else byte-identical to R3 (dout flush in the spin window,
// __syncthreads at B/C/D, per-wave flags, setprio).
__global__ __launch_bounds__(512, 2) void decoder_persist(
    const u16* __restrict__ Wcat, const float* __restrict__ bsum,
    const u16* __restrict__ fcWb, const float* __restrict__ fcb,
    const float* __restrict__ c0,
    u16* __restrict__ hb0, u16* __restrict__ hb1, const u16* __restrict__ outb,
    float* __restrict__ dout, u32* __restrict__ flags)
{
  __shared__ __align__(16) u16  Alds[32 * AST];   // 32 x (512 h | 128 out | 8 pad)
  __shared__ __align__(16) float gbuf[4096];      // 4 gates x 32 x 32 exchange

  const int tid  = threadIdx.x;
  const int wid  = tid >> 6, lane = tid & 63;
  const int l31  = lane & 31, q2 = lane >> 5;     // MFMA: col = lane&31, k-half = lane>>5
  const int mb   = blockIdx.x & 15;               // group (co-XCD under round-robin; perf-only)
  const int nb   = blockIdx.x >> 4;               // col-slice 0..15
  const int R    = mb * 32;
  u32* gf = flags + mb * 16;

  const bool isfc = (wid >= 4);
  const int  wc   = (wid - 4) * 32;               // fc out-col base (fc waves only)

  // ---- resident weights: 40 x v8s = 160 regs/lane (AGPR-backed) ----
  v8s wfrag[40];
  if (!isfc) {
    const u16* wr = Wcat + (u64)(wid * 512 + nb * 32 + l31) * KK + q2 * 8;
    #pragma unroll
    for (int kc = 0; kc < 40; ++kc) wfrag[kc] = *reinterpret_cast<const v8s*>(wr + kc * 16);
  } else {
    const u16* fr = fcWb + (u64)(wc + l31) * H_ + q2 * 8;
    #pragma unroll
    for (int kc = 0; kc < 32; ++kc) wfrag[kc] = *reinterpret_cast<const v8s*>(fr + kc * 16);
    #pragma unroll
    for (int kc = 32; kc < 40; ++kc) wfrag[kc] = (v8s){0,0,0,0,0,0,0,0};
  }
  const float bias0 = isfc ? fcb[wc + l31] : bsum[wid * 512 + nb * 32 + l31];

  // dout ownership: out-col (wc+l31) written by wg nb == col>>3 (8 cols/wg)
  const bool dopred = isfc && (((wc + l31) >> 3) == nb);

  // deferred dout state: 16 outputs of fc-act held in regs, flushed next iter
  float oreg[16];
  float* dpend = nullptr;

  // c state: 2 elems/thread: (crow, ccol..ccol+1) of the wg's 32x32 h-tile
  const int crow = tid >> 4, ccol = (tid * 2) & 31;
  float cv0 = c0[(R + crow) * H_ + nb * 32 + ccol];
  float cv1 = c0[(R + crow) * H_ + nb * 32 + ccol + 1];

  for (int t = 0; t <= NSTEP; ++t) {
    const u16* hsrc = (t & 1) ? hb1 : hb0;

    // ---- flush deferred dout (issued before the poll: progresses during
    //      the spin, acked long before any drain point) ----
    if (dopred && dpend) {
      #pragma unroll
      for (int r = 0; r < 16; ++r) {
        int row = (r & 3) + 8 * (r >> 2) + 4 * q2;
        __builtin_nontemporal_store(oreg[r], dpend + (R + row) * I_ + wc + l31);
      }
      dpend = nullptr;
    }

    // ---- per-wave poll: wave w needs slices {2w, 2w+1} for its gather ----
    if (t > 0) {
      const u32 tt = (u32)t;
      for (;;) {
        u32 f = fpoll(gf + 2 * wid + (lane & 1));
        if (__all((int)(f >= tt))) break;
      }
      __asm__ volatile("" ::: "memory");
    }

    // ---- gather: all waves issue 8 u64 loads for h-cols [64w, 64w+64) ----
    u64 tmp[8];
    #pragma unroll
    for (int k = 0; k < 8; ++k) {
      int v = k * 64 + lane;
      int row = v >> 4, c16 = v & 15;
      tmp[k] = ld64(hsrc + (R + row) * H_ + wid * 64 + c16 * 4);
    }
    // waves 0-3 (cols 0-255 = phase-1a input) commit to LDS immediately
    if (!isfc) {
      #pragma unroll
      for (int k = 0; k < 8; ++k) {
        int v = k * 64 + lane;
        int row = v >> 4, c16 = v & 15;
        *reinterpret_cast<u64*>(&Alds[row * AST + wid * 64 + c16 * 4]) = tmp[k];
      }
    }
    if (t == 0) {                       // out(-1) = x[511] (preconverted)
      u64 tp2[2];
      #pragma unroll
      for (int u = 0; u < 2; ++u) {
        int v = u * 512 + tid;
        int row = v >> 5, cc = v & 31;
        tp2[u] = ld64(outb + (R + row) * I_ + cc * 4);
      }
      #pragma unroll
      for (int u = 0; u < 2; ++u) {
        int v = u * 512 + tid;
        int row = v >> 5, cc = v & 31;
        *reinterpret_cast<u64*>(&Alds[row * AST + 512 + cc * 4]) = tp2[u];
      }
    }
    bar_lds();                          // bar A1: cols [0,256) ready
                                        // (waves 4-7 cross with loads in flight)

    // ---- phase 1a: kc 0..15 (cols 0-255) ----
    v16f acc = {0.f,0.f,0.f,0.f,0.f,0.f,0.f,0.f,0.f,0.f,0.f,0.f,0.f,0.f,0.f,0.f};
    const u16* ab = &Alds[l31 * AST + q2 * 8];
    __builtin_amdgcn_s_setprio(1);
    #pragma unroll
    for (int kc = 0; kc < 16; ++kc) {
      v8s a = *reinterpret_cast<const v8s*>(ab + kc * 16);
      acc = __builtin_amdgcn_mfma_f32_32x32x16_bf16(a, wfrag[kc], acc, 0, 0, 0);
    }
    __builtin_amdgcn_s_setprio(0);

    // waves 4-7 commit their slices (loads landed under phase-1a's MFMAs)
    if (isfc) {
      __builtin_amdgcn_sched_barrier(0);   // keep the commit after phase-1a
      #pragma unroll
      for (int k = 0; k < 8; ++k) {
        int v = k * 64 + lane;
        int row = v >> 4, c16 = v & 15;
        *reinterpret_cast<u64*>(&Alds[row * AST + wid * 64 + c16 * 4]) = tmp[k];
      }
    }
    bar_lds();                          // bar A2: cols [256,512) ready

    // ---- phase 1b: kc 16..31 (cols 256-511) ----
    __builtin_amdgcn_s_setprio(1);
    #pragma unroll
    for (int kc = 16; kc < 32; ++kc) {
      v8s a = *reinterpret_cast<const v8s*>(ab + kc * 16);
      acc = __builtin_amdgcn_mfma_f32_32x32x16_bf16(a, wfrag[kc], acc, 0, 0, 0);
    }
    __builtin_amdgcn_s_setprio(0);

    // ---- fc act: out(t-1) = 2*sigmoid(.)-1 -> LDS feedback + oreg ----
    if (isfc && t > 0) {
      #pragma unroll
      for (int r = 0; r < 16; ++r) {
        int row = (r & 3) + 8 * (r >> 2) + 4 * q2;   // 32x32 C-layout
        float o = 2.f / (1.f + __expf(-(acc[r] + bias0))) - 1.f;
        oreg[r] = o;
        Alds[row * AST + 512 + wc + l31] = f2b(o);
      }
      dpend = dout + (u64)(NSTEP - t) * (B_ * I_);
    }
    __syncthreads();                    // bar B: out region ready

    if (t < NSTEP) {
      if (!isfc) {
        // ---- phase 2: k = 512..640 (out part) ----
        __builtin_amdgcn_s_setprio(1);
        #pragma unroll
        for (int kc = 32; kc < 40; ++kc) {
          v8s a = *reinterpret_cast<const v8s*>(ab + kc * 16);
          acc = __builtin_amdgcn_mfma_f32_32x32x16_bf16(a, wfrag[kc], acc, 0, 0, 0);
        }
        __builtin_amdgcn_s_setprio(0);
        // ---- gate activation -> gbuf ----
        #pragma unroll
        for (int r = 0; r < 16; ++r) {
          int row = (r & 3) + 8 * (r >> 2) + 4 * q2;
          float z = acc[r] + bias0;
          float a2 = (wid == 2) ? tanh_fast(z) : 1.f / (1.f + __expf(-z));
          gbuf[wid * 1024 + row * 32 + l31] = a2;
        }
      }
      __syncthreads();                  // bar C: gbuf ready

      // ---- cell: c in regs, h(t+1) packed u32 -> L3 ----
      u16* hdst = (t & 1) ? hb0 : hb1;
      v2f ig = *reinterpret_cast<const v2f*>(&gbuf[       crow * 32 + ccol]);
      v2f fg = *reinterpret_cast<const v2f*>(&gbuf[1024 + crow * 32 + ccol]);
      v2f gg = *reinterpret_cast<const v2f*>(&gbuf[2048 + crow * 32 + ccol]);
      v2f og = *reinterpret_cast<const v2f*>(&gbuf[3072 + crow * 32 + ccol]);
      float cn0 = fg[0] * cv0 + ig[0] * gg[0];
      float cn1 = fg[1] * cv1 + ig[1] * gg[1];
      cv0 = cn0; cv1 = cn1;
      u32 packed = (u32)f2b(og[0] * tanh_fast(cn0)) | ((u32)f2b(og[1] * tanh_fast(cn1)) << 16);
      st32(hdst + (R + crow) * H_ + nb * 32 + ccol, packed);
      __syncthreads();                  // bar D: vmcnt(0) drain, h acked at L3
      __asm__ volatile("" ::: "memory");
      if (tid == 0) fst(gf + nb, (u32)(t + 1));
    }
  }

  // ---- final dout flush (out(511), computed at t = NSTEP) ----
  if (dopred && dpend) {
    #pragma unroll
    for (int r = 0; r < 16; ++r) {
      int row = (r & 3) + 8 * (r >> 2) + 4 * q2;
      __builtin_nontemporal_store(oreg[r], dpend + (R + row) * I_ + wc + l31);
    }
  }
}

extern "C" void kernel_launch(void* const* d_in, const int* in_sizes, int n_in,
                              void* d_out, int out_size, void* d_ws, size_t ws_size,
                              hipStream_t stream)
{
  const float* x   = (const float*)d_in[0];
  // d_in[1] = enc_hiddens: unused by the reference
  const float* h0  = (const float*)d_in[2];
  const float* c0  = (const float*)d_in[3];
  const float* Wih = (const float*)d_in[4];
  const float* Whh = (const float*)d_in[5];
  const float* bih = (const float*)d_in[6];
  const float* bhh = (const float*)d_in[7];
  const float* fcW = (const float*)d_in[8];
  const float* fcb = (const float*)d_in[9];

  char* p = (char*)d_ws;
  u16*   Wcat  = (u16*)p;   p += 2048LL * 640 * 2;
  u16*   fcWb  = (u16*)p;   p += 128 * 512 * 2;
  float* bsum  = (float*)p; p += 2048 * 4;
  u16*   hb0   = (u16*)p;   p += 512 * 512 * 2;
  u16*   hb1   = (u16*)p;   p += 512 * 512 * 2;
  u16*   outb  = (u16*)p;   p += 512 * 128 * 2;
  u32*   flags = (u32*)p;   p += 256 * 4;
  float* dout  = (float*)d_out;

  init_kernel<<<6666, 256, 0, stream>>>(x, h0, Wih, Whh, bih, bhh, fcW,
                                        Wcat, fcWb, bsum, hb0, outb, flags);
  decoder_persist<<<256, 512, 0, stream>>>(Wcat, bsum, fcWb, fcb, c0,
                                           hb0, hb1, outb, dout, flags);
}